// Round 14
// baseline (196.392 us; speedup 1.0000x reference)
//
#include <hip/hip_runtime.h>
#include <math.h>

#define NB 4
#define NS 2048
#define DMODEL 1024
#define DSPACE 64
#define NPOOL 512
#define NHEADS 6
#define NTOK (NB * NS)            // 8192
#define PROJN (NHEADS * DSPACE)   // 384
#define EPSF 1e-8f

// ---------------- K1: normalize neuron_emb rows [0,2048) -> embT[64][2048]
__global__ __launch_bounds__(256) void k_norm_emb(const float* __restrict__ emb,
                                                  float* __restrict__ embT) {
    int row  = blockIdx.x * 4 + (threadIdx.x >> 6);
    int lane = threadIdx.x & 63;
    float v  = emb[row * DSPACE + lane];
    float ss = v * v;
#pragma unroll
    for (int off = 32; off >= 1; off >>= 1) ss += __shfl_xor(ss, off, 64);
    float nrm = sqrtf(ss) + EPSF;
    embT[lane * 2048 + row] = v / nrm;
}

// ---------------- K2: proj = X @ W + b  (no split-K)
// Tile 64 rows x 64 cols, 256 threads = 4 waves; wave w owns 16 cols.
// W operand via wave-uniform pointer -> scalar s_load (SMEM pipe, zero DS).
// X staged in 16KB dbuf LDS; 1 conflict-free ds_read_b32 per kk per lane.
// DS/wave/step ~230cyc << VALU 1024cyc -> VALU-bound (~41us floor).
__global__ __launch_bounds__(256) void k_proj(const float* __restrict__ X,
                                              const float* __restrict__ W,
                                              const float* __restrict__ bias,
                                              float* __restrict__ P) {
    __shared__ float Xt[2][32 * 64];    // [kk][row], 8KB per buffer
    const int tid  = threadIdx.x;
    const int bm   = blockIdx.x * 64;
    const int bn   = blockIdx.y * 64;
    const int lane = tid & 63;
    // wave-uniform column base -> scalar W loads
    const int cbase = __builtin_amdgcn_readfirstlane(bn + (tid >> 6) * 16);
    // staging role: thread t stages row (t&63), kk-planes 8*(t>>6)+{0..7}
    const int srow = tid & 63;
    const int skk  = (tid >> 6) << 3;   // 0, 8, 16, 24
    const float* Xrow = X + (size_t)(bm + srow) * DMODEL + skk;

    float acc[16];
#pragma unroll
    for (int j = 0; j < 16; ++j) acc[j] = 0.f;

    const int nsteps = DMODEL / 32;     // 32
    float4 xa = *(const float4*)&Xrow[0];
    float4 xb = *(const float4*)&Xrow[4];

    {   // prologue: stage step 0 into buffer 0
        float* d = Xt[0];
        d[(skk + 0) * 64 + srow] = xa.x; d[(skk + 1) * 64 + srow] = xa.y;
        d[(skk + 2) * 64 + srow] = xa.z; d[(skk + 3) * 64 + srow] = xa.w;
        d[(skk + 4) * 64 + srow] = xb.x; d[(skk + 5) * 64 + srow] = xb.y;
        d[(skk + 6) * 64 + srow] = xb.z; d[(skk + 7) * 64 + srow] = xb.w;
    }

    for (int s = 0; s < nsteps; ++s) {
        if (s + 1 < nsteps) {           // prefetch next step into regs
            xa = *(const float4*)&Xrow[(s + 1) * 32 + 0];
            xb = *(const float4*)&Xrow[(s + 1) * 32 + 4];
        }
        __syncthreads();
        if (s + 1 < nsteps) {           // stage next step into other buffer
            float* d = Xt[(s + 1) & 1];
            d[(skk + 0) * 64 + srow] = xa.x; d[(skk + 1) * 64 + srow] = xa.y;
            d[(skk + 2) * 64 + srow] = xa.z; d[(skk + 3) * 64 + srow] = xa.w;
            d[(skk + 4) * 64 + srow] = xb.x; d[(skk + 5) * 64 + srow] = xb.y;
            d[(skk + 6) * 64 + srow] = xb.z; d[(skk + 7) * 64 + srow] = xb.w;
        }
        const float* xc = Xt[s & 1];
        const float* wk = W + (size_t)(s * 32) * PROJN + cbase;   // uniform
#pragma unroll
        for (int kk = 0; kk < 32; ++kk) {
            float a = xc[kk * 64 + lane];                 // ds_read_b32, no conflict
            const float* wr = wk + (size_t)kk * PROJN;    // uniform -> s_load
            float4 w0 = *(const float4*)&wr[0];
            float4 w1 = *(const float4*)&wr[4];
            float4 w2 = *(const float4*)&wr[8];
            float4 w3 = *(const float4*)&wr[12];
            acc[ 0] = fmaf(a, w0.x, acc[ 0]); acc[ 1] = fmaf(a, w0.y, acc[ 1]);
            acc[ 2] = fmaf(a, w0.z, acc[ 2]); acc[ 3] = fmaf(a, w0.w, acc[ 3]);
            acc[ 4] = fmaf(a, w1.x, acc[ 4]); acc[ 5] = fmaf(a, w1.y, acc[ 5]);
            acc[ 6] = fmaf(a, w1.z, acc[ 6]); acc[ 7] = fmaf(a, w1.w, acc[ 7]);
            acc[ 8] = fmaf(a, w2.x, acc[ 8]); acc[ 9] = fmaf(a, w2.y, acc[ 9]);
            acc[10] = fmaf(a, w2.z, acc[10]); acc[11] = fmaf(a, w2.w, acc[11]);
            acc[12] = fmaf(a, w3.x, acc[12]); acc[13] = fmaf(a, w3.y, acc[13]);
            acc[14] = fmaf(a, w3.z, acc[14]); acc[15] = fmaf(a, w3.w, acc[15]);
        }
    }

    // epilogue: row bm+lane, cols cbase..cbase+15 (each wave distinct cols)
    float o[16];
#pragma unroll
    for (int j = 0; j < 16; ++j) o[j] = acc[j] + bias[cbase + j];
    float* dst = &P[(size_t)(bm + lane) * PROJN + cbase];
    *(float4*)&dst[0]  = *(float4*)&o[0];
    *(float4*)&dst[4]  = *(float4*)&o[4];
    *(float4*)&dst[8]  = *(float4*)&o[8];
    *(float4*)&dst[12] = *(float4*)&o[12];
}

// compare-exchange keeping larger value at index a (descending order)
#define CE(arr, a, b) { float _hi = fmaxf(arr[a], arr[b]); arr[b] = fminf(arr[a], arr[b]); arr[a] = _hi; }

#define SORT8(s) \
    CE(s,0,1) CE(s,2,3) CE(s,4,5) CE(s,6,7) \
    CE(s,0,2) CE(s,1,3) CE(s,4,6) CE(s,5,7) \
    CE(s,1,2) CE(s,5,6) \
    CE(s,0,4) CE(s,1,5) CE(s,2,6) CE(s,3,7) \
    CE(s,2,4) CE(s,3,5) \
    CE(s,1,2) CE(s,3,4) CE(s,5,6)

// xor-lane exchange: ds_swizzle for off<=16; shfl for 32 (R8-proven idioms)
#define SWZ(v, IMM) __int_as_float(__builtin_amdgcn_ds_swizzle(__float_as_int(v), IMM))

#define BFLY_LEVEL(XCHG) { \
    float q[4][8]; \
    _Pragma("unroll") \
    for (int tt = 0; tt < 4; ++tt) { \
        _Pragma("unroll") \
        for (int i = 0; i < 8; ++i) { float _x = s[tt][i]; q[tt][i] = XCHG(_x); } \
    } \
    _Pragma("unroll") \
    for (int tt = 0; tt < 4; ++tt) { \
        float c[8]; \
        c[0] = fmaxf(s[tt][0], q[tt][7]); c[1] = fmaxf(s[tt][1], q[tt][6]); \
        c[2] = fmaxf(s[tt][2], q[tt][5]); c[3] = fmaxf(s[tt][3], q[tt][4]); \
        c[4] = fmaxf(s[tt][4], q[tt][3]); c[5] = fmaxf(s[tt][5], q[tt][2]); \
        c[6] = fmaxf(s[tt][6], q[tt][1]); c[7] = fmaxf(s[tt][7], q[tt][0]); \
        CE(c,0,4) CE(c,1,5) CE(c,2,6) CE(c,3,7) \
        CE(c,0,2) CE(c,1,3) CE(c,4,6) CE(c,5,7) \
        CE(c,0,1) CE(c,2,3) CE(c,4,5) CE(c,6,7) \
        _Pragma("unroll") \
        for (int i = 0; i < 8; ++i) s[tt][i] = c[i]; \
    } }

#define X1(v)  SWZ(v, 0x041F)
#define X2(v)  SWZ(v, 0x081F)
#define X4(v)  SWZ(v, 0x101F)
#define X8(v)  SWZ(v, 0x201F)
#define X16(v) SWZ(v, 0x401F)
#define X32(v) __shfl_xor(v, 32, 64)

// ---------------- K3: logits + softmax + top8 + dense write (R13 form)
// ZERO LDS: h via wave-uniform pointer -> scalar s_load on the SMEM pipe.
__global__ __launch_bounds__(256, 2) void k_router(const float* __restrict__ hfinal,
                                                   const float* __restrict__ embT,
                                                   float* __restrict__ out) {
    const int head = blockIdx.y;
    const int tid  = threadIdx.x;
    const int wid  = tid >> 6;
    const int lane = tid & 63;
    const int so = (head == 2) ? 512 : (head == 3 || head == 4) ? 1024
                 : (head == 5) ? 1536 : 0;

    const int tbase = __builtin_amdgcn_readfirstlane(blockIdx.x * 32 + (wid << 3));
    const float* hrow  = hfinal + (size_t)tbase * PROJN + head * DSPACE;  // uniform
    const float* ebase = embT + so + (lane << 3);

    float acc[8][8];
#pragma unroll
    for (int t = 0; t < 8; ++t)
#pragma unroll
        for (int j = 0; j < 8; ++j) acc[t][j] = 0.f;

    for (int dc = 0; dc < DSPACE; dc += 2) {      // 2 dims/chunk: e = 16 VGPR
        float e[2][8];
#pragma unroll
        for (int dd = 0; dd < 2; ++dd) {
            const float* er = ebase + (size_t)(dc + dd) * 2048;
            *(float4*)&e[dd][0] = *(const float4*)&er[0];
            *(float4*)&e[dd][4] = *(const float4*)&er[4];
        }
#pragma unroll
        for (int dd = 0; dd < 2; ++dd) {
#pragma unroll
            for (int t = 0; t < 8; ++t) {
                float hv = hrow[t * PROJN + dc + dd];   // uniform -> s_load
#pragma unroll
                for (int j = 0; j < 8; ++j) acc[t][j] = fmaf(hv, e[dd][j], acc[t][j]);
            }
        }
    }

    const size_t obase = ((size_t)head * NTOK + tbase) * NPOOL;

    // ---- top-k: two groups of 4 tokens, phases interleaved across tokens
#pragma unroll
    for (int g = 0; g < 2; ++g) {
        float l[4][8], s[4][8];
#pragma unroll
        for (int tt = 0; tt < 4; ++tt)
#pragma unroll
            for (int j = 0; j < 8; ++j) {
                l[tt][j] = acc[4 * g + tt][j];
                s[tt][j] = l[tt][j];
            }

        SORT8(s[0]) SORT8(s[1]) SORT8(s[2]) SORT8(s[3])

        BFLY_LEVEL(X1)
        BFLY_LEVEL(X2)
        BFLY_LEVEL(X4)
        BFLY_LEVEL(X8)
        BFLY_LEVEL(X16)
        BFLY_LEVEL(X32)

        unsigned gtm[4], eqm[4]; int own[4], inc[4];
#pragma unroll
        for (int tt = 0; tt < 4; ++tt) {
            const float T = s[tt][7];
            unsigned g_ = 0, e_ = 0; int cg = 0, ce = 0;
#pragma unroll
            for (int j = 0; j < 8; ++j) {
                if (l[tt][j] > T)       { g_ |= 1u << j; ++cg; }
                else if (l[tt][j] == T) { e_ |= 1u << j; ++ce; }
            }
            gtm[tt] = g_; eqm[tt] = e_;
            own[tt] = (ce << 8) | cg;
            inc[tt] = own[tt];
        }
#pragma unroll
        for (int off = 1; off < 64; off <<= 1) {
            int v0 = __shfl_up(inc[0], off, 64);
            int v1 = __shfl_up(inc[1], off, 64);
            int v2 = __shfl_up(inc[2], off, 64);
            int v3 = __shfl_up(inc[3], off, 64);
            if (lane >= off) { inc[0] += v0; inc[1] += v1; inc[2] += v2; inc[3] += v3; }
        }

#pragma unroll
        for (int tt = 0; tt < 4; ++tt) {
            const float T = s[tt][7];
            const float m = s[tt][0];
            int tot  = __shfl(inc[tt], 63, 64);
            int need = 8 - (tot & 0xff);
            int eqpre = (inc[tt] - own[tt]) >> 8;
            unsigned sel = gtm[tt];
#pragma unroll
            for (int j = 0; j < 8; ++j) {
                if ((eqm[tt] >> j) & 1u) { if (eqpre < need) sel |= 1u << j; ++eqpre; }
            }

            float s8 = 0.f;
#pragma unroll
            for (int i = 0; i < 8; ++i) s8 += __expf(s[tt][i] - m);
            float invd = 1.0f / s8;

            float o[8];
#pragma unroll
            for (int j = 0; j < 8; ++j)
                o[j] = ((sel >> j) & 1u) ? __expf(l[tt][j] - m) * invd : 0.0f;
            float4* dst = (float4*)&out[obase + (size_t)(4 * g + tt) * NPOOL + (lane << 3)];
            dst[0] = *(float4*)&o[0];
            dst[1] = *(float4*)&o[4];
        }
    }
}

extern "C" void kernel_launch(void* const* d_in, const int* in_sizes, int n_in,
                              void* d_out, int out_size, void* d_ws, size_t ws_size,
                              hipStream_t stream) {
    const float* x   = (const float*)d_in[0];
    const float* W   = (const float*)d_in[1];
    const float* b   = (const float*)d_in[2];
    const float* emb = (const float*)d_in[3];
    float* out  = (float*)d_out;
    float* embT = (float*)d_ws;                       // 64*2048 f32 = 512 KB
    float* proj = embT + 64 * 2048;                   // 8192*384 f32 = 12.58 MB

    k_norm_emb<<<dim3(512), dim3(256), 0, stream>>>(emb, embT);
    dim3 g2(NTOK / 64, PROJN / 64);
    k_proj<<<g2, dim3(256), 0, stream>>>(x, W, b, proj);
    dim3 g3(NTOK / 32, NHEADS);
    k_router<<<g3, dim3(256), 0, stream>>>(proj, embT, out);
}